// Round 7
// baseline (416.223 us; speedup 1.0000x reference)
//
#include <hip/hip_runtime.h>
#include <hip/hip_bf16.h>
#include <hip/hip_cooperative_groups.h>

namespace cg = cooperative_groups;

// Problem constants (from reference)
#define BB    16
#define LQ    64
#define LD    2048
#define HH    1024
#define DIM   128
#define MAXK  513          // LD/PF + 1 with PF=4
#define SCH   9            // ceil(513/64) cluster chunks for simmax
#define GRID  132          // 132 blocks x 16 waves = 2112 units exactly
#define NTH   1024

typedef __attribute__((ext_vector_type(8))) short short8;
typedef __attribute__((ext_vector_type(4))) float f32x4;

__device__ __forceinline__ float b2f(ushort u) {
    union { float f; unsigned int u32; } c; c.u32 = ((unsigned int)u) << 16; return c.f;
}
__device__ __forceinline__ ushort f2b_rn(float f) {
    unsigned int x = __float_as_uint(f);
    return (ushort)((x + 0x7fffu + ((x >> 16) & 1u)) >> 16);
}

// async global->LDS, 16B/lane; LDS dest = wave-uniform base + lane*16,
// global src is PER-LANE (enables pre-swizzled-source staging).
__device__ __forceinline__ void gld16(void* lds, const void* g) {
    __builtin_amdgcn_global_load_lds(
        (const __attribute__((address_space(1))) unsigned int*)g,
        (__attribute__((address_space(3))) unsigned int*)lds,
        16, 0, 0);
}

// LDS union, exactly 64 KB (r5 bug: a separate __shared__ array overflowed).
union ShMem {
    uint4  wbuf[4096];            // [n=128][u'=32] 16B units (encode W quarter)
    ushort tile[128][72];         // prep transpose staging (blocks 0..15)
    int    red[16];               // prep kvals reduction   (blocks 16..31)
    struct {
        ushort Qh[64 * 136];
        ushort Ql[64 * 136];
        ushort Ch[64 * 136];
        float  cn[64];
    } sm;                         // simmax staging (52.5 KB)
};

// ---------------------------------------------------------------------------
// One kernel, two modes:
//   stage = -1 : cooperative launch, all stages with grid.sync between.
//   stage = 0..3 : plain launch of one stage (host fallback when cooperative
//                  launch is rejected; r6 failed because a too-large coop
//                  grid (264 > runtime max) was launched UNCHECKED -> no-op).
// Geometry: 132 blocks x 1024 thr (16 waves), 64 KB LDS. Co-residency needs
// only 1 block/CU (132 <= 256) -- safe under any occupancy model.
__global__ __launch_bounds__(NTH, 4) void fused_kernel(
    const float*  __restrict__ Xq,      // [1024][H]
    const float*  __restrict__ Xd,      // [32768][H]
    const float*  __restrict__ W,       // [H][DIM]
    const float*  __restrict__ bias,    // [DIM]
    const int*    __restrict__ q_mask,  // [1024]
    const int*    __restrict__ d_mask,  // [32768]
    const int*    __restrict__ labels,  // [32768]
    const int*    __restrict__ pf,      // [1]
    float*        __restrict__ q_repr,  // [1024][DIM]
    float*        __restrict__ sums,    // [BB][MAXK][DIM]
    float*        __restrict__ pmax,    // [BB][SCH][4][64]
    int*          __restrict__ kvals,   // [BB]
    ushort*       __restrict__ Wt,      // [DIM][H] bf16 rounded
    float*        __restrict__ out,     // [BB]
    int           stage)
{
    __shared__ ShMem sh;
    const int bid = blockIdx.x, t = threadIdx.x;
    const int w = t >> 6, lane = t & 63;
    const int m16 = lane & 15, quad = lane >> 4;
    const bool all = (stage < 0);

    // ---------------- stage 0: prep ----------------
    if (all || stage == 0) {
        if (bid < 16) {
            // transpose+round 64 h-rows x 128 n-cols of W -> Wt
            const int h0 = bid * 64;
            #pragma unroll
            for (int i = 0; i < 8; ++i) {            // 64*128/1024
                int flat = i * NTH + t;
                int r = flat >> 7, c = flat & 127;
                sh.tile[c][r] = f2b_rn(W[(h0 + r) * DIM + c]);
            }
            __syncthreads();
            {                                         // 128 rows x 8 uint4 = 1024
                int n = t >> 3, uu = t & 7;
                uint4 v = *(const uint4*)&sh.tile[n][uu * 8];
                *(uint4*)&Wt[(long)n * HH + h0 + uu * 8] = v;
            }
        } else if (bid < 32) {
            int b = bid - 16;
            int s = 0;
            for (int i = t; i < LD; i += NTH) s += (d_mask[b * LD + i] > 0) ? 1 : 0;
            #pragma unroll
            for (int m = 1; m < 64; m <<= 1) s += __shfl_xor(s, m);
            if (lane == 0) sh.red[w] = s;
            __syncthreads();
            if (t == 0) {
                int v = 0;
                #pragma unroll
                for (int i = 0; i < 16; ++i) v += sh.red[i];
                if (v < 2) v = 2;
                int pfv = pf[0];
                if (pfv < 1 || pfv > LD) pfv = 4;     // defensive
                kvals[b] = v / pfv + 1;
            }
        } else {
            // zero sums: 262,656 float4 over 100 blocks
            const int total4 = (BB * MAXK * DIM) / 4;
            float4* s4 = (float4*)sums;
            const float4 z = make_float4(0.f, 0.f, 0.f, 0.f);
            for (int i = (bid - 32) * NTH + t; i < total4; i += 100 * NTH)
                s4[i] = z;
        }
    }
    if (all) { __syncthreads(); __threadfence(); cg::this_grid().sync(); }

    // ---------------- stage 1: encode + fused pooled-scatter ----------------
    // W-stationary: LDS = one K-quarter of W^T (128n x 256k bf16, XOR-swizzled
    // via pre-swizzled gld16 source). A streams global->regs, ring depth 3.
    // Every wave owns exactly one 16-row unit (2112 units = 132*16 waves).
    if (all || stage == 1) {
        const int unit = bid * 16 + w;            // 0..2111
        const bool isq = unit >= 2048;
        const long row0 = isq ? (long)(unit - 2048) * 16 : (long)unit * 16;
        const float* Xb = isq ? Xq : Xd;
        const float* aptr = Xb + (row0 + m16) * HH + quad * 8;

        f32x4 acc[8];
        #pragma unroll
        for (int j = 0; j < 8; ++j) acc[j] = (f32x4){0.f, 0.f, 0.f, 0.f};

        const int sw8 = m16 & 7;
        const ushort* Wu = (const ushort*)sh.wbuf;

        float4 ast[4][2];                          // A ring, static indices
        ast[0][0] = *(const float4*)(aptr);
        ast[0][1] = *(const float4*)(aptr + 4);
        ast[1][0] = *(const float4*)(aptr + 32);
        ast[1][1] = *(const float4*)(aptr + 36);
        ast[2][0] = *(const float4*)(aptr + 64);
        ast[2][1] = *(const float4*)(aptr + 68);

        #pragma unroll
        for (int p = 0; p < 4; ++p) {
            __syncthreads();                       // done reading W_{p-1}
            #pragma unroll
            for (int i = 0; i < 4; ++i) {          // wave stages 256 slots
                int Si = w * 256 + i * 64 + lane;  // per-lane slot
                int n = Si >> 5, up = Si & 31;
                const ushort* src = Wt + (long)n * HH + (p * 32 + (up ^ (n & 7))) * 8;
                gld16(&sh.wbuf[w * 256 + i * 64], src);
            }
            __syncthreads();                       // W_p landed (vmcnt drain)
            #pragma unroll
            for (int cc = 0; cc < 8; ++cc) {
                const int c = p * 8 + cc;          // global chunk 0..31
                if (c + 3 < 32) {
                    ast[(c + 3) & 3][0] = *(const float4*)(aptr + (c + 3) * 32);
                    ast[(c + 3) & 3][1] = *(const float4*)(aptr + (c + 3) * 32 + 4);
                }
                float av[8];
                *(float4*)(av)     = ast[c & 3][0];
                *(float4*)(av + 4) = ast[c & 3][1];
                short8 ah, al;
                #pragma unroll
                for (int j = 0; j < 8; ++j) {
                    unsigned int ux = __float_as_uint(av[j]);
                    ah[j] = (short)(ux >> 16);
                    float hif = __uint_as_float(ux & 0xffff0000u);
                    al[j] = (short)(__float_as_uint(av[j] - hif) >> 16);
                }
                #pragma unroll
                for (int ct = 0; ct < 8; ++ct) {
                    short8 bf = *(const short8*)
                        &Wu[(ct * 16 + m16) * 256 + ((cc * 4 + quad) ^ sw8) * 8];
                    acc[ct] = __builtin_amdgcn_mfma_f32_16x16x32_bf16(ah, bf, acc[ct], 0, 0, 0);
                    acc[ct] = __builtin_amdgcn_mfma_f32_16x16x32_bf16(al, bf, acc[ct], 0, 0, 0);
                }
            }
        }

        // epilogue: bias, in-wave row norm, mask, store/scatter
        float bia[8];
        #pragma unroll
        for (int ct = 0; ct < 8; ++ct) bia[ct] = bias[ct * 16 + m16];

        float vv[8][4];
        float ssp[4] = {0.f, 0.f, 0.f, 0.f};
        #pragma unroll
        for (int ct = 0; ct < 8; ++ct)
            #pragma unroll
            for (int r = 0; r < 4; ++r) {
                vv[ct][r] = acc[ct][r] + bia[ct];
                ssp[r] += vv[ct][r] * vv[ct][r];
            }
        #pragma unroll
        for (int r = 0; r < 4; ++r) {
            ssp[r] += __shfl_xor(ssp[r], 1);
            ssp[r] += __shfl_xor(ssp[r], 2);
            ssp[r] += __shfl_xor(ssp[r], 4);
            ssp[r] += __shfl_xor(ssp[r], 8);
        }

        #pragma unroll
        for (int r = 0; r < 4; ++r) {
            long rowg = row0 + quad * 4 + r;
            float scale = 1.0f / fmaxf(sqrtf(ssp[r]), 1e-12f);
            if (isq) {
                scale *= (float)q_mask[rowg];
                #pragma unroll
                for (int ct = 0; ct < 8; ++ct)
                    q_repr[rowg * DIM + ct * 16 + m16] = vv[ct][r] * scale;
            } else if (d_mask[rowg] > 0) {
                int b = (int)(rowg >> 11);
                int seg = labels[rowg] % kvals[b];
                float* sp = sums + ((long)b * MAXK + seg) * DIM + m16;
                #pragma unroll
                for (int ct = 0; ct < 8; ++ct)
                    atomicAdd(sp + ct * 16, vv[ct][r] * scale);
            }
        }
    }
    if (all) { __threadfence(); cg::this_grid().sync(); }

    // ---------------- stage 2: simmax ----------------
    // item = (b, 64-cluster chunk): 16*9 = 144 items over 132 blocks.
    // Wave w: q-rows (w&3)*16, cluster group (w>>2)*16.
    if (all || stage == 2) {
        for (int item = bid; item < BB * SCH; item += GRID) {
            __syncthreads();                       // LDS reuse guard
            const int b = item & 15, ch = item >> 4;

            #pragma unroll
            for (int i = 0; i < 2; ++i) {          // stage Q: 2048 float4
                int flat = i * NTH + t;
                int row = flat >> 5, c4 = flat & 31;
                float4 v = *(const float4*)(q_repr + ((long)b * LQ + row) * DIM + c4 * 4);
                float x[4]; *(float4*)x = v;
                ushort4 h, l;
                ushort* hp = (ushort*)&h; ushort* lp = (ushort*)&l;
                #pragma unroll
                for (int j = 0; j < 4; ++j) {
                    unsigned int ux = __float_as_uint(x[j]);
                    hp[j] = (ushort)(ux >> 16);
                    lp[j] = f2b_rn(x[j] - __uint_as_float(ux & 0xffff0000u));
                }
                *(ushort4*)&sh.sm.Qh[row * 136 + c4 * 4] = h;
                *(ushort4*)&sh.sm.Ql[row * 136 + c4 * 4] = l;
            }
            #pragma unroll
            for (int i = 0; i < 2; ++i) {          // stage C: 64 rows
                int flat = i * NTH + t;
                int row = flat >> 5, c4 = flat & 31;
                int kk = ch * 64 + row;
                float4 v = (kk < MAXK)
                    ? *(const float4*)(sums + ((long)b * MAXK + kk) * DIM + c4 * 4)
                    : make_float4(0.f, 0.f, 0.f, 0.f);
                ushort4 h; ushort* hp = (ushort*)&h;
                hp[0] = f2b_rn(v.x); hp[1] = f2b_rn(v.y);
                hp[2] = f2b_rn(v.z); hp[3] = f2b_rn(v.w);
                *(ushort4*)&sh.sm.Ch[row * 136 + c4 * 4] = h;
            }
            __syncthreads();

            if (t < 256) {                         // per-cluster inv-norms
                int c = t >> 2, q4 = t & 3;
                float ssv = 0.f;
                #pragma unroll
                for (int j = 0; j < 16; ++j) {
                    unsigned int u = *(const unsigned int*)&sh.sm.Ch[c * 136 + q4 * 32 + j * 2];
                    float x0 = b2f((ushort)u), x1 = b2f((ushort)(u >> 16));
                    ssv += x0 * x0 + x1 * x1;
                }
                ssv += __shfl_xor(ssv, 1);
                ssv += __shfl_xor(ssv, 2);
                if (q4 == 0) sh.sm.cn[c] = (ssv > 1e-24f) ? rsqrtf(ssv) : 0.f;
            }
            __syncthreads();

            const int qb = (w & 3) * 16, cb = (w >> 2) * 16;
            f32x4 a2 = (f32x4){0.f, 0.f, 0.f, 0.f};
            #pragma unroll
            for (int kc = 0; kc < 4; ++kc) {
                short8 qh = *(const short8*)&sh.sm.Qh[(qb + m16) * 136 + kc * 32 + quad * 8];
                short8 ql = *(const short8*)&sh.sm.Ql[(qb + m16) * 136 + kc * 32 + quad * 8];
                short8 cf = *(const short8*)&sh.sm.Ch[(cb + m16) * 136 + kc * 32 + quad * 8];
                a2 = __builtin_amdgcn_mfma_f32_16x16x32_bf16(qh, cf, a2, 0, 0, 0);
                a2 = __builtin_amdgcn_mfma_f32_16x16x32_bf16(ql, cf, a2, 0, 0, 0);
            }
            int kb = kvals[b];
            #pragma unroll
            for (int r = 0; r < 4; ++r) {
                int cll = cb + m16;
                int cl = ch * 64 + cll;
                float sim = a2[r] * sh.sm.cn[cll];
                float mx = (cl < kb) ? sim : -1e4f;
                mx = fmaxf(mx, __shfl_xor(mx, 1));
                mx = fmaxf(mx, __shfl_xor(mx, 2));
                mx = fmaxf(mx, __shfl_xor(mx, 4));
                mx = fmaxf(mx, __shfl_xor(mx, 8));
                if (m16 == 0)
                    pmax[(((long)b * SCH + ch) * 4 + (w >> 2)) * 64 + qb + quad * 4 + r] = mx;
            }
        }
    }
    if (all) { __threadfence(); cg::this_grid().sync(); }

    // ---------------- stage 3: final ----------------
    if (all || stage == 3) {
        if (bid < BB && t < 64) {
            float m = -3e38f;
            #pragma unroll
            for (int s2 = 0; s2 < SCH * 4; ++s2)
                m = fmaxf(m, pmax[(long)bid * (SCH * 4 * 64) + s2 * 64 + t]);
            m *= (float)q_mask[bid * LQ + t];
            #pragma unroll
            for (int sh2 = 1; sh2 < 64; sh2 <<= 1) m += __shfl_xor(m, sh2);
            if (t == 0) out[bid] = m;
        }
    }
}

// ---------------------------------------------------------------------------
extern "C" void kernel_launch(void* const* d_in, const int* in_sizes, int n_in,
                              void* d_out, int out_size, void* d_ws, size_t ws_size,
                              hipStream_t stream) {
    const float* q_hidden = (const float*)d_in[0];
    const float* d_hidden = (const float*)d_in[1];
    const float* W        = (const float*)d_in[2];
    const float* bias     = (const float*)d_in[3];
    const int*   q_mask   = (const int*)d_in[4];
    const int*   d_mask   = (const int*)d_in[5];
    const int*   labels   = (const int*)d_in[6];
    const int*   pf       = (const int*)d_in[7];

    float* ws     = (float*)d_ws;
    float* q_repr = ws;                                   // 131,072 f
    float* sums   = q_repr + (long)BB * LQ * DIM;         // 1,050,624 f
    float* pmaxb  = sums + (long)BB * MAXK * DIM;         // 16*9*4*64 = 36,864 f
    int*   kvals  = (int*)(pmaxb + (long)BB * SCH * 4 * 64);  // 16
    ushort* Wt    = (ushort*)(kvals + 16);                // 131,072 bf16
    float* outp   = (float*)d_out;

    int stage_all = -1;
    void* args[] = { (void*)&q_hidden, (void*)&d_hidden, (void*)&W, (void*)&bias,
                     (void*)&q_mask, (void*)&d_mask, (void*)&labels, (void*)&pf,
                     (void*)&q_repr, (void*)&sums, (void*)&pmaxb, (void*)&kvals,
                     (void*)&Wt, (void*)&outp, (void*)&stage_all };
    hipError_t err = hipLaunchCooperativeKernel((const void*)fused_kernel,
                                                dim3(GRID), dim3(NTH),
                                                args, 0, stream);
    if (err != hipSuccess) {
        // Fallback: 4 plain stage launches (no grid.sync on this path).
        for (int s = 0; s < 4; ++s)
            fused_kernel<<<GRID, NTH, 0, stream>>>(
                q_hidden, d_hidden, W, bias, q_mask, d_mask, labels, pf,
                q_repr, sums, pmaxb, kvals, Wt, outp, s);
    }
}

// Round 9
// 280.285 us; speedup vs baseline: 1.4850x; 1.4850x over previous
//
#include <hip/hip_runtime.h>
#include <hip/hip_bf16.h>

// Problem constants (from reference)
#define BB    16
#define LQ    64
#define LD    2048
#define HH    1024
#define DIM   128
#define MAXK  513          // LD/PF + 1 with PF=4
#define SCH   9            // ceil(513/64) cluster chunks for simmax

typedef __attribute__((ext_vector_type(8))) short short8;
typedef __attribute__((ext_vector_type(4))) float f32x4;

__device__ __forceinline__ float b2f(ushort u) {
    union { float f; unsigned int u32; } c; c.u32 = ((unsigned int)u) << 16; return c.f;
}
__device__ __forceinline__ ushort f2b_rn(float f) {
    unsigned int x = __float_as_uint(f);
    return (ushort)((x + 0x7fffu + ((x >> 16) & 1u)) >> 16);
}

// async global->LDS, 16B/lane; LDS dest = wave-uniform base + lane*16,
// global src is PER-LANE (enables pre-swizzled-source staging).
__device__ __forceinline__ void gld16(void* lds, const void* g) {
    __builtin_amdgcn_global_load_lds(
        (const __attribute__((address_space(1))) unsigned int*)g,
        (__attribute__((address_space(3))) unsigned int*)lds,
        16, 0, 0);
}

// ---------------------------------------------------------------------------
// Fused prep (r3-proven):
//   blocks [0,16):   LDS-tile transpose+round W -> Wt bf16 (coalesced writes)
//   blocks [16,32):  kvals per batch
//   blocks [32,288): zero sums (replaces hipMemsetAsync dispatch)
__global__ __launch_bounds__(256) void prep_kb_kernel(
    const float* __restrict__ W,
    const int*   __restrict__ d_mask,
    const int*   __restrict__ pf,
    ushort*      __restrict__ Wt,
    int*         __restrict__ kvals,
    float*       __restrict__ sums)
{
    int bid = blockIdx.x, t = threadIdx.x;
    if (bid < 16) {
        __shared__ ushort tile[128][72];   // stride 72 ushorts = 144B
        const int h0 = bid * 64;
        #pragma unroll
        for (int i = 0; i < 32; ++i) {     // 64*128/256
            int flat = i * 256 + t;
            int r = flat >> 7, c = flat & 127;
            tile[c][r] = f2b_rn(W[(long)(h0 + r) * DIM + c]);
        }
        __syncthreads();
        #pragma unroll
        for (int i = 0; i < 4; ++i) {      // 128 rows x 8 uint4 = 1024 uint4
            int flat = i * 256 + t;
            int n = flat >> 3, u = flat & 7;
            uint4 v = *(const uint4*)&tile[n][u * 8];
            *(uint4*)&Wt[(long)n * HH + h0 + u * 8] = v;
        }
    } else if (bid < 32) {
        __shared__ int red[4];
        int b = bid - 16;
        int lane = t & 63, wave = t >> 6;
        int s = 0;
        for (int i = t; i < LD; i += 256) s += (d_mask[b * LD + i] > 0) ? 1 : 0;
        #pragma unroll
        for (int m = 1; m < 64; m <<= 1) s += __shfl_xor(s, m);
        if (lane == 0) red[wave] = s;
        __syncthreads();
        if (t == 0) {
            int v = red[0] + red[1] + red[2] + red[3];
            if (v < 2) v = 2;
            int pfv = pf[0];
            if (pfv < 1 || pfv > LD) pfv = 4;   // defensive
            kvals[b] = v / pfv + 1;
        }
    } else {
        const int total4 = (BB * MAXK * DIM) / 4;
        float4* s4 = (float4*)sums;
        const float4 z = make_float4(0.f, 0.f, 0.f, 0.f);
        for (int i = (bid - 32) * 256 + t; i < total4; i += 256 * 256)
            s4[i] = z;
    }
}

// ---------------------------------------------------------------------------
// Encode (W-stationary, SINGLE bf16 pass), launched twice:
//   <<<8,512>>>  isq=1 : q rows (64 units)
//   <<<256,512>>> isq=0: d rows (2048 units) + fused pooled-scatter
// Each wave owns one 16-row unit x all 128 cols; LDS holds one K-quarter of
// W^T (128n x 256k bf16 = 64 KB, XOR-swizzled via pre-swizzled gld16 source);
// A streams global->regs (ring depth 3). acc persists across 4 phases.
// Single-pass: A rounded bf16-rn (harness threshold 0.3675 is bf16-tolerant;
// est. absmax ~0.02-0.1) -- halves MFMA + split-VALU vs r4's hi+lo.
// [r9: resubmission of r8 verbatim -- r8's "container failed twice" had no
//  compiler/test output; source audit found no defect (64KB static LDS ran in
//  r4/r7; no use-before-decl; static ring indices); infra-flake hypothesis.]
__global__ __launch_bounds__(512, 4) void encode_kernel(
    const float*  __restrict__ X,       // [nrows][H]
    const ushort* __restrict__ Wt,      // [DIM][H] bf16 rounded
    const float*  __restrict__ bias,    // [DIM]
    const int*    __restrict__ mask,    // [nrows]
    const int*    __restrict__ labels,  // [32768] (d only)
    const int*    __restrict__ kvals,   // [BB]    (d only)
    float*        __restrict__ sums,    // [BB][MAXK][DIM] (d only)
    float*        __restrict__ q_repr,  // [1024][DIM]     (q only)
    int           isq)
{
    __shared__ __align__(16) uint4 Wlds[4096];   // 64 KB

    const int t = threadIdx.x;
    const int w = t >> 6, lane = t & 63;
    const int m16 = lane & 15, quad = lane >> 4;

    const int unit = blockIdx.x * 8 + w;
    const long row0 = (long)unit * 16;
    const float* aptr = X + (row0 + m16) * HH + quad * 8;

    f32x4 acc[8];
    #pragma unroll
    for (int j = 0; j < 8; ++j) acc[j] = (f32x4){0.f, 0.f, 0.f, 0.f};

    const int sw8 = m16 & 7;
    const ushort* Wu = (const ushort*)Wlds;

    float4 ast[4][2];                          // A ring, static indices
    ast[0][0] = *(const float4*)(aptr);
    ast[0][1] = *(const float4*)(aptr + 4);
    ast[1][0] = *(const float4*)(aptr + 32);
    ast[1][1] = *(const float4*)(aptr + 36);
    ast[2][0] = *(const float4*)(aptr + 64);
    ast[2][1] = *(const float4*)(aptr + 68);

    #pragma unroll
    for (int p = 0; p < 4; ++p) {
        __syncthreads();                       // done reading W_{p-1}
        #pragma unroll
        for (int i = 0; i < 8; ++i) {          // wave stages slots [w*512,+512)
            int Si = w * 512 + i * 64 + lane;  // per-lane slot
            int n = Si >> 5, up = Si & 31;
            const ushort* src = Wt + (long)n * HH + (p * 32 + (up ^ (n & 7))) * 8;
            gld16(&Wlds[w * 512 + i * 64], src);
        }
        __syncthreads();                       // W_p landed (vmcnt drain)
        #pragma unroll
        for (int cc = 0; cc < 8; ++cc) {
            const int c = p * 8 + cc;          // global chunk 0..31
            if (c + 3 < 32) {
                ast[(c + 3) & 3][0] = *(const float4*)(aptr + (c + 3) * 32);
                ast[(c + 3) & 3][1] = *(const float4*)(aptr + (c + 3) * 32 + 4);
            }
            float av[8];
            *(float4*)(av)     = ast[c & 3][0];
            *(float4*)(av + 4) = ast[c & 3][1];
            short8 ah;
            #pragma unroll
            for (int j = 0; j < 8; ++j) ah[j] = (short)f2b_rn(av[j]);
            #pragma unroll
            for (int ct = 0; ct < 8; ++ct) {
                short8 bf = *(const short8*)
                    &Wu[(ct * 16 + m16) * 256 + ((cc * 4 + quad) ^ sw8) * 8];
                acc[ct] = __builtin_amdgcn_mfma_f32_16x16x32_bf16(ah, bf, acc[ct], 0, 0, 0);
            }
        }
    }

    // epilogue: bias, in-wave row norm, mask, store/scatter
    float bia[8];
    #pragma unroll
    for (int ct = 0; ct < 8; ++ct) bia[ct] = bias[ct * 16 + m16];

    float vv[8][4];
    float ssp[4] = {0.f, 0.f, 0.f, 0.f};
    #pragma unroll
    for (int ct = 0; ct < 8; ++ct)
        #pragma unroll
        for (int r = 0; r < 4; ++r) {
            vv[ct][r] = acc[ct][r] + bia[ct];
            ssp[r] += vv[ct][r] * vv[ct][r];
        }
    #pragma unroll
    for (int r = 0; r < 4; ++r) {
        ssp[r] += __shfl_xor(ssp[r], 1);
        ssp[r] += __shfl_xor(ssp[r], 2);
        ssp[r] += __shfl_xor(ssp[r], 4);
        ssp[r] += __shfl_xor(ssp[r], 8);
    }

    #pragma unroll
    for (int r = 0; r < 4; ++r) {
        long rowg = row0 + quad * 4 + r;
        float scale = 1.0f / fmaxf(sqrtf(ssp[r]), 1e-12f);
        if (isq) {
            scale *= (float)mask[rowg];
            #pragma unroll
            for (int ct = 0; ct < 8; ++ct)
                q_repr[rowg * DIM + ct * 16 + m16] = vv[ct][r] * scale;
        } else if (mask[rowg] > 0) {
            int b = (int)(rowg >> 11);
            int seg = labels[rowg] % kvals[b];
            float* sp = sums + ((long)b * MAXK + seg) * DIM + m16;
            #pragma unroll
            for (int ct = 0; ct < 8; ++ct)
                atomicAdd(sp + ct * 16, vv[ct][r] * scale);
        }
    }
}

// ---------------------------------------------------------------------------
// Sim via MFMA (r3-proven, hi/lo Q kept for precision): block = (b, 64-cluster
// chunk). Stage Q (split bf16) and C (rounded bf16) in LDS, MFMA over K=128,
// per-cluster rsqrt, shuffle-max -> pmax[b][chunk][64].
__global__ __launch_bounds__(256) void simmax_kernel(
    const float* __restrict__ q_repr,   // [B][LQ][DIM]
    const float* __restrict__ sums,     // [B][MAXK][DIM] raw cluster sums
    const int*   __restrict__ kvals,
    float*       __restrict__ pmax)     // [B][SCH][64]
{
    __shared__ __align__(16) ushort Qh[64 * 136];
    __shared__ __align__(16) ushort Ql[64 * 136];
    __shared__ __align__(16) ushort Ch[64 * 136];
    __shared__ float cn[64];

    int b = blockIdx.x / SCH, chunk = blockIdx.x % SCH;
    int t = threadIdx.x, w = t >> 6, lane = t & 63;
    int m16 = lane & 15, quad = lane >> 4;

    #pragma unroll
    for (int i = 0; i < 8; ++i) {
        int flat = i * 256 + t;          // float4 index
        int row = flat >> 5, c4 = flat & 31;
        float4 v = *(const float4*)(q_repr + ((long)b * LQ + row) * DIM + c4 * 4);
        float x[4]; *(float4*)x = v;
        ushort4 h, l;
        ushort* hp = (ushort*)&h; ushort* lp = (ushort*)&l;
        #pragma unroll
        for (int j = 0; j < 4; ++j) {
            unsigned int ux = __float_as_uint(x[j]);
            hp[j] = (ushort)(ux >> 16);
            lp[j] = f2b_rn(x[j] - __uint_as_float(ux & 0xffff0000u));
        }
        *(ushort4*)&Qh[row * 136 + c4 * 4] = h;
        *(ushort4*)&Ql[row * 136 + c4 * 4] = l;
    }
    #pragma unroll
    for (int i = 0; i < 8; ++i) {
        int flat = i * 256 + t;
        int row = flat >> 5, c4 = flat & 31;
        int kk = chunk * 64 + row;
        float4 v = (kk < MAXK)
            ? *(const float4*)(sums + ((long)b * MAXK + kk) * DIM + c4 * 4)
            : make_float4(0.f, 0.f, 0.f, 0.f);
        ushort4 h; ushort* hp = (ushort*)&h;
        hp[0] = f2b_rn(v.x); hp[1] = f2b_rn(v.y);
        hp[2] = f2b_rn(v.z); hp[3] = f2b_rn(v.w);
        *(ushort4*)&Ch[row * 136 + c4 * 4] = h;
    }
    __syncthreads();

    {
        int c = w * 16 + m16;
        float ssv = 0.f;
        #pragma unroll
        for (int j = 0; j < 16; ++j) {
            unsigned int u = *(const unsigned int*)&Ch[c * 136 + quad * 32 + j * 2];
            float x0 = b2f((ushort)u), x1 = b2f((ushort)(u >> 16));
            ssv += x0 * x0 + x1 * x1;
        }
        ssv += __shfl_xor(ssv, 16);
        ssv += __shfl_xor(ssv, 32);
        if (quad == 0) cn[c] = (ssv > 1e-24f) ? rsqrtf(ssv) : 0.f;
    }
    __syncthreads();

    f32x4 acc[4];
    #pragma unroll
    for (int j = 0; j < 4; ++j) acc[j] = (f32x4){0.f, 0.f, 0.f, 0.f};

    #pragma unroll
    for (int kc = 0; kc < 4; ++kc) {
        short8 qh = *(const short8*)&Qh[(w * 16 + m16) * 136 + kc * 32 + quad * 8];
        short8 ql = *(const short8*)&Ql[(w * 16 + m16) * 136 + kc * 32 + quad * 8];
        #pragma unroll
        for (int ct = 0; ct < 4; ++ct) {
            short8 cf = *(const short8*)&Ch[(ct * 16 + m16) * 136 + kc * 32 + quad * 8];
            acc[ct] = __builtin_amdgcn_mfma_f32_16x16x32_bf16(qh, cf, acc[ct], 0, 0, 0);
            acc[ct] = __builtin_amdgcn_mfma_f32_16x16x32_bf16(ql, cf, acc[ct], 0, 0, 0);
        }
    }

    int kb = kvals[b];
    #pragma unroll
    for (int r = 0; r < 4; ++r) {
        float mx = -1e4f;
        #pragma unroll
        for (int ct = 0; ct < 4; ++ct) {
            int cl = chunk * 64 + ct * 16 + m16;
            float sim = acc[ct][r] * cn[ct * 16 + m16];
            mx = fmaxf(mx, (cl < kb) ? sim : -1e4f);
        }
        mx = fmaxf(mx, __shfl_xor(mx, 1));
        mx = fmaxf(mx, __shfl_xor(mx, 2));
        mx = fmaxf(mx, __shfl_xor(mx, 4));
        mx = fmaxf(mx, __shfl_xor(mx, 8));
        if (m16 == 0)
            pmax[((long)b * SCH + chunk) * 64 + w * 16 + quad * 4 + r] = mx;
    }
}

// ---------------------------------------------------------------------------
// Final: per batch, max over chunks, *q_mask, sum over rows -> out[b]
__global__ __launch_bounds__(64) void final_kernel(
    const float* __restrict__ pmax,
    const int*   __restrict__ q_mask,
    float*       __restrict__ out)
{
    int b = blockIdx.x, r = threadIdx.x;
    float m = -3e38f;
    #pragma unroll
    for (int c = 0; c < SCH; ++c)
        m = fmaxf(m, pmax[((long)b * SCH + c) * 64 + r]);
    m *= (float)q_mask[b * LQ + r];
    #pragma unroll
    for (int sh = 1; sh < 64; sh <<= 1) m += __shfl_xor(m, sh);
    if (r == 0) out[b] = m;
}

// ---------------------------------------------------------------------------
extern "C" void kernel_launch(void* const* d_in, const int* in_sizes, int n_in,
                              void* d_out, int out_size, void* d_ws, size_t ws_size,
                              hipStream_t stream) {
    const float* q_hidden = (const float*)d_in[0];
    const float* d_hidden = (const float*)d_in[1];
    const float* W        = (const float*)d_in[2];
    const float* bias     = (const float*)d_in[3];
    const int*   q_mask   = (const int*)d_in[4];
    const int*   d_mask   = (const int*)d_in[5];
    const int*   labels   = (const int*)d_in[6];
    const int*   pf       = (const int*)d_in[7];

    float* ws     = (float*)d_ws;
    float* q_repr = ws;                                   // 131,072 f
    float* sums   = q_repr + (long)BB * LQ * DIM;         // 1,050,624 f
    float* pmaxb  = sums + (long)BB * MAXK * DIM;         // 16*9*64 = 9,216 f
    int*   kvals  = (int*)(pmaxb + BB * SCH * 64);        // 16
    ushort* Wt    = (ushort*)(kvals + 16);                // 131,072 bf16

    prep_kb_kernel<<<288, 256, 0, stream>>>(W, d_mask, pf, Wt, kvals, sums);
    // q first (8 blocks, warms Wt in L2), then d (256 blocks, exact balance)
    encode_kernel<<<8, 512, 0, stream>>>(q_hidden, Wt, bias, q_mask,
                                         labels, kvals, sums, q_repr, 1);
    encode_kernel<<<256, 512, 0, stream>>>(d_hidden, Wt, bias, d_mask,
                                           labels, kvals, sums, q_repr, 0);
    simmax_kernel<<<BB * SCH, 256, 0, stream>>>(q_repr, sums, kvals, pmaxb);
    final_kernel<<<BB, 64, 0, stream>>>(pmaxb, q_mask, (float*)d_out);
}

// Round 11
// 255.891 us; speedup vs baseline: 1.6266x; 1.0953x over previous
//
#include <hip/hip_runtime.h>
#include <hip/hip_bf16.h>

// Problem constants (from reference)
#define BB    16
#define LQ    64
#define LD    2048
#define HH    1024
#define DIM   128
#define MAXK  513          // LD/PF + 1 with PF=4
#define SCH   9            // ceil(513/64) cluster chunks for simmax

typedef __attribute__((ext_vector_type(8))) short short8;
typedef __attribute__((ext_vector_type(4))) float f32x4;

__device__ __forceinline__ float b2f(ushort u) {
    union { float f; unsigned int u32; } c; c.u32 = ((unsigned int)u) << 16; return c.f;
}
__device__ __forceinline__ ushort f2b_rn(float f) {
    unsigned int x = __float_as_uint(f);
    return (ushort)((x + 0x7fffu + ((x >> 16) & 1u)) >> 16);
}

// async global->LDS, 16B/lane; LDS dest = wave-uniform base + lane*16,
// global src is PER-LANE (enables pre-swizzled-source staging).
// [r10 lesson: asm global_load_dwordx4 with "=v" output is UNSOUND for
//  prefetch rings -- compiler may copy/realloc the dest reg while the load
//  is in flight (absmax 1.5e5). gld16's issue point is fixed and the
//  barrier vmcnt(0) drain is the landing fence -> stage A via LDS instead.]
__device__ __forceinline__ void gld16(void* lds, const void* g) {
    __builtin_amdgcn_global_load_lds(
        (const __attribute__((address_space(1))) unsigned int*)g,
        (__attribute__((address_space(3))) unsigned int*)lds,
        16, 0, 0);
}

// ---------------------------------------------------------------------------
// Fused prep (r3-proven):
//   blocks [0,16):   LDS-tile transpose+round W -> Wt bf16 (coalesced writes)
//   blocks [16,32):  kvals per batch
//   blocks [32,288): zero sums
__global__ __launch_bounds__(256) void prep_kb_kernel(
    const float* __restrict__ W,
    const int*   __restrict__ d_mask,
    const int*   __restrict__ pf,
    ushort*      __restrict__ Wt,
    int*         __restrict__ kvals,
    float*       __restrict__ sums)
{
    int bid = blockIdx.x, t = threadIdx.x;
    if (bid < 16) {
        __shared__ ushort tile[128][72];   // stride 72 ushorts = 144B
        const int h0 = bid * 64;
        #pragma unroll
        for (int i = 0; i < 32; ++i) {     // 64*128/256
            int flat = i * 256 + t;
            int r = flat >> 7, c = flat & 127;
            tile[c][r] = f2b_rn(W[(long)(h0 + r) * DIM + c]);
        }
        __syncthreads();
        #pragma unroll
        for (int i = 0; i < 4; ++i) {      // 128 rows x 8 uint4 = 1024 uint4
            int flat = i * 256 + t;
            int n = flat >> 3, u = flat & 7;
            uint4 v = *(const uint4*)&tile[n][u * 8];
            *(uint4*)&Wt[(long)n * HH + h0 + u * 8] = v;
        }
    } else if (bid < 32) {
        __shared__ int red[4];
        int b = bid - 16;
        int lane = t & 63, wave = t >> 6;
        int s = 0;
        for (int i = t; i < LD; i += 256) s += (d_mask[b * LD + i] > 0) ? 1 : 0;
        #pragma unroll
        for (int m = 1; m < 64; m <<= 1) s += __shfl_xor(s, m);
        if (lane == 0) red[wave] = s;
        __syncthreads();
        if (t == 0) {
            int v = red[0] + red[1] + red[2] + red[3];
            if (v < 2) v = 2;
            int pfv = pf[0];
            if (pfv < 1 || pfv > LD) pfv = 4;   // defensive
            kvals[b] = v / pfv + 1;
        }
    } else {
        const int total4 = (BB * MAXK * DIM) / 4;
        float4* s4 = (float4*)sums;
        const float4 z = make_float4(0.f, 0.f, 0.f, 0.f);
        for (int i = (bid - 32) * 256 + t; i < total4; i += 256 * 256)
            s4[i] = z;
    }
}

// ---------------------------------------------------------------------------
// Encode (W-stationary, single bf16 pass, ALL staging via gld16+barrier):
//   <<<16,256>>>  isq=1 : q rows (64 units)
//   <<<512,256>>> isq=0 : d rows (2048 units) + fused pooled-scatter
// 4 waves/block, wave = one 16-row unit x all 128 cols. LDS 64 KB:
//   W  = [0,2048) u4 units: K-eighth of W^T, [n=128][u'=16], XOR-swz source
//   A  = [2048,4096): per-wave 512 units = 4 chunk-slots x [16r][8u],
//        r0-proven source swizzle (lane&7)^((lane>>3)&7)
// Per phase p (8 phases x 4 chunks): barrier -> issue 8 W + 8 A gld16
// back-to-back (16KB/wave in flight; r9's sunk C++ loads exposed latency
// per-chunk, VGPR=56 proved ring never materialized) -> barrier (vmcnt0
// drain = everything landed) -> 4 chunks of pure-LDS compute, no waits.
// 2 blocks/CU (128KB LDS). No inline asm anywhere.
__global__ __launch_bounds__(256, 2) void encode_kernel(
    const float*  __restrict__ X,       // [nrows][H]
    const ushort* __restrict__ Wt,      // [DIM][H] bf16 rounded
    const float*  __restrict__ bias,    // [DIM]
    const int*    __restrict__ mask,    // [nrows]
    const int*    __restrict__ labels,  // [32768] (d only)
    const int*    __restrict__ kvals,   // [BB]    (d only)
    float*        __restrict__ sums,    // [BB][MAXK][DIM] (d only)
    float*        __restrict__ q_repr,  // [1024][DIM]     (q only)
    int           isq)
{
    __shared__ __align__(16) uint4 lds[4096];    // 64 KB

    const int t = threadIdx.x;
    const int w = t >> 6, lane = t & 63;
    const int m16 = lane & 15, quad = lane >> 4;

    const int unit = blockIdx.x * 4 + w;
    const long row0 = (long)unit * 16;

    f32x4 acc[8];
    #pragma unroll
    for (int j = 0; j < 8; ++j) acc[j] = (f32x4){0.f, 0.f, 0.f, 0.f};

    const int sw8 = m16 & 7;
    const ushort* Wu = (const ushort*)lds;           // W region as ushorts
    const float4* Af = (const float4*)lds;           // A region as float4
    const int Abase = 2048 + w * 512;                // per-wave A base (u4 units)

    // A staging source (r0-proven swizzle): op j covers rows j*8..j*8+7;
    // lane l -> row j*8+(l>>3), k-part ((l&7)^((l>>3)&7))*4 (+ chunk*32)
    const float* gA = X + (row0 + (lane >> 3)) * HH
                        + (((lane & 7) ^ ((lane >> 3) & 7)) * 4);

    #pragma unroll
    for (int p = 0; p < 8; ++p) {
        __syncthreads();                   // consumers of phase p-1 done
        // stage W eighth p: 2048 u4 units, wave w fills [w*512, w*512+512)
        #pragma unroll
        for (int i = 0; i < 8; ++i) {
            int Si = w * 512 + i * 64 + lane;        // per-lane slot
            int n = Si >> 4, up = Si & 15;
            const ushort* src = Wt + (long)n * HH + (p * 16 + (up ^ (n & 7))) * 8;
            gld16(&lds[w * 512 + i * 64], src);
        }
        // stage A chunks p*4..p*4+3 into slots 0..3 (2 gld16 each)
        #pragma unroll
        for (int s = 0; s < 4; ++s) {
            const long ko = (long)(p * 4 + s) * 32;
            gld16(&lds[Abase + s * 128], gA + ko);           // rows 0..7
            gld16(&lds[Abase + s * 128 + 64], gA + 8 * HH + ko); // rows 8..15
        }
        __syncthreads();                   // vmcnt(0) drain: W_p + A slots landed
        #pragma unroll
        for (int cc = 0; cc < 4; ++cc) {
            float4 va0 = Af[Abase + cc * 128 + m16 * 8 + ((2 * quad) ^ sw8)];
            float4 va1 = Af[Abase + cc * 128 + m16 * 8 + ((2 * quad + 1) ^ sw8)];
            float av[8];
            *(float4*)(av)     = va0;
            *(float4*)(av + 4) = va1;
            short8 ah;
            #pragma unroll
            for (int j = 0; j < 8; ++j) ah[j] = (short)f2b_rn(av[j]);
            #pragma unroll
            for (int ct = 0; ct < 8; ++ct) {
                short8 bf = *(const short8*)
                    &Wu[(ct * 16 + m16) * 128 + (((cc * 4 + quad)) ^ sw8) * 8];
                acc[ct] = __builtin_amdgcn_mfma_f32_16x16x32_bf16(ah, bf, acc[ct], 0, 0, 0);
            }
        }
    }

    // epilogue: bias, in-wave row norm, mask, store/scatter (r9-proven)
    float bia[8];
    #pragma unroll
    for (int ct = 0; ct < 8; ++ct) bia[ct] = bias[ct * 16 + m16];

    float vv[8][4];
    float ssp[4] = {0.f, 0.f, 0.f, 0.f};
    #pragma unroll
    for (int ct = 0; ct < 8; ++ct)
        #pragma unroll
        for (int r = 0; r < 4; ++r) {
            vv[ct][r] = acc[ct][r] + bia[ct];
            ssp[r] += vv[ct][r] * vv[ct][r];
        }
    #pragma unroll
    for (int r = 0; r < 4; ++r) {
        ssp[r] += __shfl_xor(ssp[r], 1);
        ssp[r] += __shfl_xor(ssp[r], 2);
        ssp[r] += __shfl_xor(ssp[r], 4);
        ssp[r] += __shfl_xor(ssp[r], 8);
    }

    #pragma unroll
    for (int r = 0; r < 4; ++r) {
        long rowg = row0 + quad * 4 + r;
        float scale = 1.0f / fmaxf(sqrtf(ssp[r]), 1e-12f);
        if (isq) {
            scale *= (float)mask[rowg];
            #pragma unroll
            for (int ct = 0; ct < 8; ++ct)
                q_repr[rowg * DIM + ct * 16 + m16] = vv[ct][r] * scale;
        } else if (mask[rowg] > 0) {
            int b = (int)(rowg >> 11);
            int seg = labels[rowg] % kvals[b];
            float* sp = sums + ((long)b * MAXK + seg) * DIM + m16;
            #pragma unroll
            for (int ct = 0; ct < 8; ++ct)
                atomicAdd(sp + ct * 16, vv[ct][r] * scale);
        }
    }
}

// ---------------------------------------------------------------------------
// Sim via MFMA (r3-proven, hi/lo Q kept for precision): block = (b, 64-cluster
// chunk). Stage Q (split bf16) and C (rounded bf16) in LDS, MFMA over K=128,
// per-cluster rsqrt, shuffle-max -> pmax[b][chunk][64].
__global__ __launch_bounds__(256) void simmax_kernel(
    const float* __restrict__ q_repr,   // [B][LQ][DIM]
    const float* __restrict__ sums,     // [B][MAXK][DIM] raw cluster sums
    const int*   __restrict__ kvals,
    float*       __restrict__ pmax)     // [B][SCH][64]
{
    __shared__ __align__(16) ushort Qh[64 * 136];
    __shared__ __align__(16) ushort Ql[64 * 136];
    __shared__ __align__(16) ushort Ch[64 * 136];
    __shared__ float cn[64];

    int b = blockIdx.x / SCH, chunk = blockIdx.x % SCH;
    int t = threadIdx.x, w = t >> 6, lane = t & 63;
    int m16 = lane & 15, quad = lane >> 4;

    #pragma unroll
    for (int i = 0; i < 8; ++i) {
        int flat = i * 256 + t;          // float4 index
        int row = flat >> 5, c4 = flat & 31;
        float4 v = *(const float4*)(q_repr + ((long)b * LQ + row) * DIM + c4 * 4);
        float x[4]; *(float4*)x = v;
        ushort4 h, l;
        ushort* hp = (ushort*)&h; ushort* lp = (ushort*)&l;
        #pragma unroll
        for (int j = 0; j < 4; ++j) {
            unsigned int ux = __float_as_uint(x[j]);
            hp[j] = (ushort)(ux >> 16);
            lp[j] = f2b_rn(x[j] - __uint_as_float(ux & 0xffff0000u));
        }
        *(ushort4*)&Qh[row * 136 + c4 * 4] = h;
        *(ushort4*)&Ql[row * 136 + c4 * 4] = l;
    }
    #pragma unroll
    for (int i = 0; i < 8; ++i) {
        int flat = i * 256 + t;
        int row = flat >> 5, c4 = flat & 31;
        int kk = chunk * 64 + row;
        float4 v = (kk < MAXK)
            ? *(const float4*)(sums + ((long)b * MAXK + kk) * DIM + c4 * 4)
            : make_float4(0.f, 0.f, 0.f, 0.f);
        ushort4 h; ushort* hp = (ushort*)&h;
        hp[0] = f2b_rn(v.x); hp[1] = f2b_rn(v.y);
        hp[2] = f2b_rn(v.z); hp[3] = f2b_rn(v.w);
        *(ushort4*)&Ch[row * 136 + c4 * 4] = h;
    }
    __syncthreads();

    {
        int c = w * 16 + m16;
        float ssv = 0.f;
        #pragma unroll
        for (int j = 0; j < 16; ++j) {
            unsigned int u = *(const unsigned int*)&Ch[c * 136 + quad * 32 + j * 2];
            float x0 = b2f((ushort)u), x1 = b2f((ushort)(u >> 16));
            ssv += x0 * x0 + x1 * x1;
        }
        ssv += __shfl_xor(ssv, 16);
        ssv += __shfl_xor(ssv, 32);
        if (quad == 0) cn[c] = (ssv > 1e-24f) ? rsqrtf(ssv) : 0.f;
    }
    __syncthreads();

    f32x4 acc[4];
    #pragma unroll
    for (int j = 0; j < 4; ++j) acc[j] = (f32x4){0.f, 0.f, 0.f, 0.f};

    #pragma unroll
    for (int kc = 0; kc < 4; ++kc) {
        short8 qh = *(const short8*)&Qh[(w * 16 + m16) * 136 + kc * 32 + quad * 8];
        short8 ql = *(const short8*)&Ql[(w * 16 + m16) * 136 + kc * 32 + quad * 8];
        #pragma unroll
        for (int ct = 0; ct < 4; ++ct) {
            short8 cf = *(const short8*)&Ch[(ct * 16 + m16) * 136 + kc * 32 + quad * 8];
            acc[ct] = __builtin_amdgcn_mfma_f32_16x16x32_bf16(qh, cf, acc[ct], 0, 0, 0);
            acc[ct] = __builtin_amdgcn_mfma_f32_16x16x32_bf16(ql, cf, acc[ct], 0, 0, 0);
        }
    }

    int kb = kvals[b];
    #pragma unroll
    for (int r = 0; r < 4; ++r) {
        float mx = -1e4f;
        #pragma unroll
        for (int ct = 0; ct < 4; ++ct) {
            int cl = chunk * 64 + ct * 16 + m16;
            float sim = acc[ct][r] * cn[ct * 16 + m16];
            mx = fmaxf(mx, (cl < kb) ? sim : -1e4f);
        }
        mx = fmaxf(mx, __shfl_xor(mx, 1));
        mx = fmaxf(mx, __shfl_xor(mx, 2));
        mx = fmaxf(mx, __shfl_xor(mx, 4));
        mx = fmaxf(mx, __shfl_xor(mx, 8));
        if (m16 == 0)
            pmax[((long)b * SCH + chunk) * 64 + w * 16 + quad * 4 + r] = mx;
    }
}

// ---------------------------------------------------------------------------
// Final: per batch, max over chunks, *q_mask, sum over rows -> out[b]
__global__ __launch_bounds__(64) void final_kernel(
    const float* __restrict__ pmax,
    const int*   __restrict__ q_mask,
    float*       __restrict__ out)
{
    int b = blockIdx.x, r = threadIdx.x;
    float m = -3e38f;
    #pragma unroll
    for (int c = 0; c < SCH; ++c)
        m = fmaxf(m, pmax[((long)b * SCH + c) * 64 + r]);
    m *= (float)q_mask[b * LQ + r];
    #pragma unroll
    for (int sh = 1; sh < 64; sh <<= 1) m += __shfl_xor(m, sh);
    if (r == 0) out[b] = m;
}

// ---------------------------------------------------------------------------
extern "C" void kernel_launch(void* const* d_in, const int* in_sizes, int n_in,
                              void* d_out, int out_size, void* d_ws, size_t ws_size,
                              hipStream_t stream) {
    const float* q_hidden = (const float*)d_in[0];
    const float* d_hidden = (const float*)d_in[1];
    const float* W        = (const float*)d_in[2];
    const float* bias     = (const float*)d_in[3];
    const int*   q_mask   = (const int*)d_in[4];
    const int*   d_mask   = (const int*)d_in[5];
    const int*   labels   = (const int*)d_in[6];
    const int*   pf       = (const int*)d_in[7];

    float* ws     = (float*)d_ws;
    float* q_repr = ws;                                   // 131,072 f
    float* sums   = q_repr + (long)BB * LQ * DIM;         // 1,050,624 f
    float* pmaxb  = sums + (long)BB * MAXK * DIM;         // 16*9*64 = 9,216 f
    int*   kvals  = (int*)(pmaxb + BB * SCH * 64);        // 16
    ushort* Wt    = (ushort*)(kvals + 16);                // 131,072 bf16

    prep_kb_kernel<<<288, 256, 0, stream>>>(W, d_mask, pf, Wt, kvals, sums);
    // q first (16 blocks, warms Wt in L2), then d (512 blocks, 2/CU)
    encode_kernel<<<16, 256, 0, stream>>>(q_hidden, Wt, bias, q_mask,
                                          labels, kvals, sums, q_repr, 1);
    encode_kernel<<<512, 256, 0, stream>>>(d_hidden, Wt, bias, d_mask,
                                           labels, kvals, sums, q_repr, 0);
    simmax_kernel<<<BB * SCH, 256, 0, stream>>>(q_repr, sums, kvals, pmaxb);
    final_kernel<<<BB, 64, 0, stream>>>(pmaxb, q_mask, (float*)d_out);
}